// Round 1
// baseline (1019.378 us; speedup 1.0000x reference)
//
#include <hip/hip_runtime.h>
#include <hip/hip_bf16.h>

typedef __attribute__((ext_vector_type(8))) short bf16x8;
typedef __attribute__((ext_vector_type(4))) float f32x4;

#define B_SZ 64
#define L_SZ 1024
#define D_SZ 64
#define SCALE 0.125f

// LDS score/P buffer: [b_local 16][q_local 16][k_local 32], padded pitches
// (multiples of 4 floats for aligned b128, +4-float rotation to break banks)
#define KP 36          // k pitch (floats)
#define BPITCH 580     // 16*KP + 4
#define SA_SZ 9280     // 16*BPITCH floats = 37.1 KB per k-group

__device__ __forceinline__ short f2bf(float f) {
    union { float f; unsigned u; } v; v.f = f;
    unsigned r = (v.u + 0x7fffu + ((v.u >> 16) & 1u)) >> 16;  // RNE
    return (short)r;
}

__device__ __forceinline__ bf16x8 cvt8(const float* __restrict__ p) {
    f32x4 a = *(const f32x4*)p;
    f32x4 b = *(const f32x4*)(p + 4);
    bf16x8 r;
    r[0] = f2bf(a[0]); r[1] = f2bf(a[1]); r[2] = f2bf(a[2]); r[3] = f2bf(a[3]);
    r[4] = f2bf(b[0]); r[5] = f2bf(b[1]); r[6] = f2bf(b[2]); r[7] = f2bf(b[3]);
    return r;
}

#define MFMA(A, Bf, C) __builtin_amdgcn_mfma_f32_16x16x32_bf16(A, Bf, C, 0, 0, 0)

// Block: 512 threads = 8 waves. Waves 0-3 -> k in [0,512), waves 4-7 -> [512,1024).
// Within a 4-wave k-group, wave r owns content-batches b_local=r*4..r*4+3 and
// pos-queries q_local=r*4..r*4+3. Tile: 16 batches x 16 queries per block.
__global__ __launch_bounds__(512, 2) void rpr_attn(
    const float* __restrict__ Q, const float* __restrict__ Kt,
    const float* __restrict__ V, const float* __restrict__ PK,
    const float* __restrict__ PV, const int* __restrict__ VLEN,
    float* __restrict__ OUT)
{
    __shared__ float SA[2][SA_SZ];   // per-k-group exchange buffer (74.2 KB)
    __shared__ float lbuf[2][256];   // per-group l sums, [g][b_local*16+q_local]

    const int tid = threadIdx.x;
    const int wave = tid >> 6, lane = tid & 63;
    const int g = wave >> 2, r = wave & 3;
    const int lane15 = lane & 15, quad = lane >> 4;
    const int b0 = blockIdx.x * 16;   // 4 batch tiles (fast dim -> co-resident, share pos via L3)
    const int q0 = blockIdx.y * 16;   // 64 query tiles

    float* sa = SA[g];

    // ---- Q fragments (loaded once; contraction dim = d, per-lane 8 consecutive d) ----
    // content A-frag: A[m=lane15 -> q][k=quad*8+j -> d], one per (b_local j, d-half)
    // pos     A-frag: A[m=lane15 -> b][k -> d],          one per (q_local j, d-half)
    bf16x8 qa[4][2], qp[4][2];
    int vl[4];
#pragma unroll
    for (int j = 0; j < 4; ++j) {
        const int bl = r * 4 + j;
        vl[j] = VLEN[b0 + bl];
        const float* pc = Q + ((b0 + bl) * L_SZ + q0 + lane15) * D_SZ + quad * 8;
        qa[j][0] = cvt8(pc); qa[j][1] = cvt8(pc + 32);
        const float* pp = Q + ((b0 + lane15) * L_SZ + q0 + bl) * D_SZ + quad * 8;
        qp[j][0] = cvt8(pp); qp[j][1] = cvt8(pp + 32);
    }

    f32x4 Oc[4][4], Op[4][4];   // content O[b][q x d], pos O[q][b x d]
#pragma unroll
    for (int j = 0; j < 4; ++j)
#pragma unroll
        for (int nt = 0; nt < 4; ++nt) {
            Oc[j][nt] = (f32x4){0.f, 0.f, 0.f, 0.f};
            Op[j][nt] = (f32x4){0.f, 0.f, 0.f, 0.f};
        }
    float l_acc = 0.f;

    const int tg = r * 64 + lane;          // 0..255 within k-group
    const int lb = tg >> 4, lq = tg & 15;  // this thread's (b_local,q_local) for l-sum

    for (int it = 0; it < 16; ++it) {
        const int kb = g * 512 + it * 32;

        // ---- phase 1: pos scores S_p[q](b x k) -> scatter to SA[b][q][k] ----
#pragma unroll
        for (int j = 0; j < 4; ++j) {
            const int ql = r * 4 + j;
#pragma unroll
            for (int c = 0; c < 2; ++c) {
                const float* bp = PK + ((q0 + ql) * L_SZ + kb + c * 16 + lane15) * D_SZ + quad * 8;
                f32x4 acc = (f32x4){0.f, 0.f, 0.f, 0.f};
                acc = MFMA(qp[j][0], cvt8(bp), acc);
                acc = MFMA(qp[j][1], cvt8(bp + 32), acc);
                // C layout: row=(quad*4+i) -> b_local, col=lane15 -> k
#pragma unroll
                for (int i = 0; i < 4; ++i)
                    sa[(quad * 4 + i) * BPITCH + ql * KP + c * 16 + lane15] = acc[i];
            }
        }
        __syncthreads();

        // ---- phase 2: content scores, combine, mask, exp -> P in SA (in-place) ----
#pragma unroll
        for (int j = 0; j < 4; ++j) {
            const int bl = r * 4 + j;
#pragma unroll
            for (int c = 0; c < 2; ++c) {
                const float* bp = Kt + ((b0 + bl) * L_SZ + kb + c * 16 + lane15) * D_SZ + quad * 8;
                f32x4 acc = (f32x4){0.f, 0.f, 0.f, 0.f};
                acc = MFMA(qa[j][0], cvt8(bp), acc);
                acc = MFMA(qa[j][1], cvt8(bp + 32), acc);
                const int kg = kb + c * 16 + lane15;
#pragma unroll
                for (int i = 0; i < 4; ++i) {
                    const int idx = bl * BPITCH + (quad * 4 + i) * KP + c * 16 + lane15;
                    const float s = (acc[i] + sa[idx]) * SCALE;
                    float e;
                    if (vl[j] == 0)       e = 1.0f;          // fully-masked row -> uniform attn
                    else if (kg < vl[j])  e = __expf(s);
                    else                  e = 0.0f;
                    sa[idx] = e;
                }
            }
        }
        __syncthreads();

        // ---- phase 3: l accumulation + both PV contractions ----
        {
            const float* row = sa + lb * BPITCH + lq * KP;
            float s = 0.f;
#pragma unroll
            for (int kk = 0; kk < 32; kk += 4) {
                f32x4 v4 = *(const f32x4*)(row + kk);
                s += v4[0] + v4[1] + v4[2] + v4[3];
            }
            l_acc += s;
        }
        // content: Oc[b] += P[b](q x k) * V[b](k x d)
#pragma unroll
        for (int j = 0; j < 4; ++j) {
            const int bl = r * 4 + j;
            const bf16x8 af = cvt8(sa + bl * BPITCH + lane15 * KP + quad * 8);
            const float* vb = V + ((b0 + bl) * L_SZ + kb + quad * 8) * D_SZ + lane15;
#pragma unroll
            for (int nt = 0; nt < 4; ++nt) {
                bf16x8 bf;
#pragma unroll
                for (int jj = 0; jj < 8; ++jj) bf[jj] = f2bf(vb[jj * D_SZ + nt * 16]);
                Oc[j][nt] = MFMA(af, bf, Oc[j][nt]);
            }
        }
        // pos: Op[q] += P[q](b x k) * pos_v[q](k x d)
#pragma unroll
        for (int j = 0; j < 4; ++j) {
            const int ql = r * 4 + j;
            const bf16x8 af = cvt8(sa + lane15 * BPITCH + ql * KP + quad * 8);
            const float* vb = PV + ((q0 + ql) * L_SZ + kb + quad * 8) * D_SZ + lane15;
#pragma unroll
            for (int nt = 0; nt < 4; ++nt) {
                bf16x8 bf;
#pragma unroll
                for (int jj = 0; jj < 8; ++jj) bf[jj] = f2bf(vb[jj * D_SZ + nt * 16]);
                Op[j][nt] = MFMA(af, bf, Op[j][nt]);
            }
        }
        __syncthreads();   // protect SA before next iteration's phase 1
    }

    // ---- epilogue: merge Oc/Op across roles and k-groups via LDS, normalize ----
    lbuf[g][tg] = l_acc;
    float* Obuf = &SA[0][0];   // 16384 floats, overlays SA (all SA traffic is done)

    if (g == 0) {
#pragma unroll
        for (int j = 0; j < 4; ++j)
#pragma unroll
            for (int nt = 0; nt < 4; ++nt)
#pragma unroll
                for (int i = 0; i < 4; ++i)
                    Obuf[((r * 4 + j) * 16 + quad * 4 + i) * 64 + nt * 16 + lane15] = Oc[j][nt][i];
    }
    __syncthreads();
    if (g == 1) {
#pragma unroll
        for (int j = 0; j < 4; ++j)
#pragma unroll
            for (int nt = 0; nt < 4; ++nt)
#pragma unroll
                for (int i = 0; i < 4; ++i)
                    Obuf[((r * 4 + j) * 16 + quad * 4 + i) * 64 + nt * 16 + lane15] += Oc[j][nt][i];
    }
    __syncthreads();
    if (g == 0) {
#pragma unroll
        for (int j = 0; j < 4; ++j)
#pragma unroll
            for (int nt = 0; nt < 4; ++nt)
#pragma unroll
                for (int i = 0; i < 4; ++i)
                    Obuf[((quad * 4 + i) * 16 + r * 4 + j) * 64 + nt * 16 + lane15] += Op[j][nt][i];
    }
    __syncthreads();
    if (g == 1) {
#pragma unroll
        for (int j = 0; j < 4; ++j)
#pragma unroll
            for (int nt = 0; nt < 4; ++nt)
#pragma unroll
                for (int i = 0; i < 4; ++i)
                    Obuf[((quad * 4 + i) * 16 + r * 4 + j) * 64 + nt * 16 + lane15] += Op[j][nt][i];
    }
    __syncthreads();

    for (int idx = tid; idx < 4096; idx += 512) {
        const int d4 = idx & 15, ql2 = (idx >> 4) & 15, bl2 = idx >> 8;
        const float li = lbuf[0][bl2 * 16 + ql2] + lbuf[1][bl2 * 16 + ql2];
        const float rl = 1.0f / li;
        f32x4 o = *(const f32x4*)&Obuf[(bl2 * 16 + ql2) * 64 + d4 * 4];
        o[0] *= rl; o[1] *= rl; o[2] *= rl; o[3] *= rl;
        *(f32x4*)&OUT[((b0 + bl2) * L_SZ + q0 + ql2) * D_SZ + d4 * 4] = o;
    }
}

extern "C" void kernel_launch(void* const* d_in, const int* in_sizes, int n_in,
                              void* d_out, int out_size, void* d_ws, size_t ws_size,
                              hipStream_t stream) {
    (void)in_sizes; (void)n_in; (void)out_size; (void)d_ws; (void)ws_size;
    const float* Q  = (const float*)d_in[0];
    const float* K  = (const float*)d_in[1];
    const float* V  = (const float*)d_in[2];
    const float* PK = (const float*)d_in[3];
    const float* PV = (const float*)d_in[4];
    const int*   VL = (const int*)d_in[5];
    float* OUT = (float*)d_out;

    dim3 grid(4, 64, 1);   // x = batch tile (fast -> co-resident pos sharing), y = query tile
    dim3 block(512, 1, 1);
    rpr_attn<<<grid, block, 0, stream>>>(Q, K, V, PK, PV, VL, OUT);
}